// Round 7
// baseline (1240.980 us; speedup 1.0000x reference)
//
#include <hip/hip_runtime.h>
#include <stdint.h>

#define H_DIM    512
#define NUM_BASES 128

typedef __attribute__((ext_vector_type(4))) float f32x4;
typedef __attribute__((ext_vector_type(8))) short bf16x8;

__device__ __forceinline__ short f32_bf16(float f) {
  union { float f; unsigned u; } x; x.f = f;
  unsigned r = x.u + 0x7FFF + ((x.u >> 16) & 1);   // RNE
  return (short)(r >> 16);
}
__device__ __forceinline__ float bf16_f32(short s) {
  union { unsigned u; float f; } x; x.u = ((unsigned)(unsigned short)s) << 16;
  return x.f;
}

__device__ __forceinline__ void gload_lds16(const void* g, void* l) {
  __builtin_amdgcn_global_load_lds(
      (const __attribute__((address_space(1))) uint32_t*)g,
      (__attribute__((address_space(3))) uint32_t*)l, 16, 0, 0);
}

// ---------------------------------------------------------------------------
// A-prep: emb [M][512] fp32 -> Ah/Al [Mpad][512] bf16 (hi/lo split, pad=0)
// ---------------------------------------------------------------------------
__global__ __launch_bounds__(256) void aprep(const float* __restrict__ A,
                                             short* __restrict__ Ah,
                                             short* __restrict__ Al,
                                             int M, int Mpad) {
  const int row = blockIdx.x * 2 + (threadIdx.x >> 7);
  const int col = (threadIdx.x & 127) * 4;
  if (row >= Mpad) return;
  float4 v = make_float4(0.f, 0.f, 0.f, 0.f);
  if (row < M) v = *(const float4*)(A + (size_t)row * H_DIM + col);
  short h0 = f32_bf16(v.x), h1 = f32_bf16(v.y), h2 = f32_bf16(v.z), h3 = f32_bf16(v.w);
  short e0 = f32_bf16(v.x - bf16_f32(h0)), e1 = f32_bf16(v.y - bf16_f32(h1));
  short e2 = f32_bf16(v.z - bf16_f32(h2)), e3 = f32_bf16(v.w - bf16_f32(h3));
  *(short4*)(Ah + (size_t)row * H_DIM + col) = make_short4(h0, h1, h2, h3);
  *(short4*)(Al + (size_t)row * H_DIM + col) = make_short4(e0, e1, e2, e3);
}

// ---------------------------------------------------------------------------
// B-prep: loop_weight [K=512][N=512] fp32 -> Bt_hi/Bt_lo [N][K] bf16
// ---------------------------------------------------------------------------
__global__ __launch_bounds__(256) void bprep(const float* __restrict__ B,
                                             short* __restrict__ Bt_hi,
                                             short* __restrict__ Bt_lo) {
  __shared__ float T[32][33];
  const int k0 = blockIdx.x * 32, n0 = blockIdx.y * 32;
  const int tid = threadIdx.x;
#pragma unroll
  for (int q = 0; q < 4; ++q) {
    int idx = tid + q * 256;
    int kk = idx >> 5, nn = idx & 31;
    T[kk][nn] = B[(k0 + kk) * H_DIM + n0 + nn];
  }
  __syncthreads();
#pragma unroll
  for (int q = 0; q < 4; ++q) {
    int idx = tid + q * 256;
    int nn = idx >> 5, kk = idx & 31;
    float v = T[kk][nn];
    short hi = f32_bf16(v);
    short lo = f32_bf16(v - bf16_f32(hi));
    Bt_hi[(size_t)(n0 + nn) * H_DIM + k0 + kk] = hi;
    Bt_lo[(size_t)(n0 + nn) * H_DIM + k0 + kk] = lo;
  }
}

// ---------------------------------------------------------------------------
// GEMM v4: A via global_load_lds into 32KB LDS (pre-swizzled source, swizzled
// ds_read_b128); B fragments straight from L2 into registers (B is 1MB,
// L2-resident, reused by all m-blocks -> LDS staging was pure overhead).
// 128x128 tile, BK=64, 4 waves, 3-term split-bf16. launch_bounds(256,3)
// -> 3 blocks/CU (was 2 with 64KB LDS).
// ---------------------------------------------------------------------------
__global__ __launch_bounds__(256, 3) void mfma_gemm4(
    const short* __restrict__ Ah,   // [Mpad][512] bf16
    const short* __restrict__ Al,
    const short* __restrict__ Bh,   // [512(n)][512(k)] bf16
    const short* __restrict__ Bl,
    const float* __restrict__ bias,
    float* __restrict__ C, int M) {
  __shared__ short sAh[8192], sAl[8192];   // 2 x 16KB

  const int tid = threadIdx.x;
  const int lane = tid & 63;
  const int wv = tid >> 6;

  // bijective XCD swizzle (m204): lin enumerates (m-row, n-tile), n inner
  const int nwg = gridDim.x;
  const int q = nwg >> 3, rmd = nwg & 7;
  const int xcd = blockIdx.x & 7, j = blockIdx.x >> 3;
  const int lin = (xcd < rmd ? xcd * (q + 1) : rmd * (q + 1) + (xcd - rmd) * q) + j;
  const int row0 = (lin >> 2) * 128;
  const int col0 = (lin & 3) * 128;

  const int wm = (wv >> 1) * 64;
  const int wn = (wv & 1) * 64;
  const int l15 = lane & 15;
  const int l4 = lane >> 4;

  const int st_rowoff = lane >> 3;
  const int st_gd = lane & 7;

  f32x4 acc[4][4] = {};

  for (int k0 = 0; k0 < H_DIM; k0 += 64) {
    // stage A tile (128 rows x 64 k) hi+lo: 8 gload_lds per wave
#pragma unroll
    for (int qq = 0; qq < 4; ++qq) {
      const int brow = wv * 32 + qq * 8;
      const int trow = brow + st_rowoff;
      const int gsh = (st_gd ^ (trow & 7)) * 8;   // inverse of read swizzle
      const size_t aoff = (size_t)(row0 + trow) * H_DIM + k0 + gsh;
      const int ldso = brow * 64;
      gload_lds16(Ah + aoff, &sAh[ldso]);
      gload_lds16(Al + aoff, &sAl[ldso]);
    }
    __syncthreads();

#pragma unroll
    for (int kk = 0; kk < 2; ++kk) {
      const int gc = kk * 4 + l4;
      bf16x8 ah[4], al[4], bh[4], bl[4];
#pragma unroll
      for (int i = 0; i < 4; ++i) {
        const int ra = wm + 16 * i + l15;
        const int sia = ra * 64 + (gc ^ (ra & 7)) * 8;
        ah[i] = *(const bf16x8*)&sAh[sia];
        al[i] = *(const bf16x8*)&sAl[sia];
        const size_t boff = (size_t)(col0 + wn + 16 * i + l15) * H_DIM + k0 + gc * 8;
        bh[i] = *(const bf16x8*)(Bh + boff);   // L2-hot register load
        bl[i] = *(const bf16x8*)(Bl + boff);
      }
#pragma unroll
      for (int i = 0; i < 4; ++i)
#pragma unroll
        for (int jj = 0; jj < 4; ++jj) {
          acc[i][jj] = __builtin_amdgcn_mfma_f32_16x16x32_bf16(ah[i], bh[jj], acc[i][jj], 0, 0, 0);
          acc[i][jj] = __builtin_amdgcn_mfma_f32_16x16x32_bf16(ah[i], bl[jj], acc[i][jj], 0, 0, 0);
          acc[i][jj] = __builtin_amdgcn_mfma_f32_16x16x32_bf16(al[i], bh[jj], acc[i][jj], 0, 0, 0);
        }
    }
    __syncthreads();
  }

  float bv[4];
#pragma unroll
  for (int jj = 0; jj < 4; ++jj) bv[jj] = bias[col0 + wn + 16 * jj + l15];
#pragma unroll
  for (int i = 0; i < 4; ++i) {
#pragma unroll
    for (int r = 0; r < 4; ++r) {
      const int grow = row0 + wm + 16 * i + l4 * 4 + r;
      if (grow < M) {
#pragma unroll
        for (int jj = 0; jj < 4; ++jj)
          C[(size_t)grow * H_DIM + col0 + wn + 16 * jj + l15] = acc[i][jj][r] + bv[jj];
      }
    }
  }
}

// ---------------------------------------------------------------------------
// CSR build: zero -> count -> single-block scan -> scatter (pre-gathered
// sorted copies of src/et/norm so edge_agg reads are contiguous).
// ---------------------------------------------------------------------------
__global__ void zero_i32(int* p, int n) {
  int i = blockIdx.x * 256 + threadIdx.x;
  if (i < n) p[i] = 0;
}

__global__ void count_deg(const int* __restrict__ dst, int* deg, int E) {
  int e = blockIdx.x * 256 + threadIdx.x;
  if (e < E) atomicAdd(&deg[dst[e]], 1);
}

__global__ __launch_bounds__(1024) void scan_deg(const int* __restrict__ deg,
                                                 int* __restrict__ ns,
                                                 int* __restrict__ cur, int M) {
  __shared__ int part[1024];
  const int tid = threadIdx.x;
  const int chunk = (M + 1023) >> 10;
  const int base = tid * chunk;
  int sum = 0;
  for (int k = 0; k < chunk; ++k) {
    int i = base + k;
    if (i < M) sum += deg[i];
  }
  part[tid] = sum;
  __syncthreads();
  const int own = sum;
  for (int off = 1; off < 1024; off <<= 1) {
    int v = (tid >= off) ? part[tid - off] : 0;
    __syncthreads();
    part[tid] += v;
    __syncthreads();
  }
  int run = part[tid] - own;   // exclusive prefix at chunk start
  for (int k = 0; k < chunk; ++k) {
    int i = base + k;
    if (i < M) {
      ns[i] = run;
      cur[i] = run;
      run += deg[i];
    }
  }
  if (tid == 1023) ns[M] = part[1023];
}

__global__ void scatter_edges(const int* __restrict__ dst, const int* __restrict__ src,
                              const int* __restrict__ et, const float* __restrict__ norm,
                              int* cur, int* __restrict__ srcs, int* __restrict__ ets,
                              float* __restrict__ norms, int E) {
  int e = blockIdx.x * 256 + threadIdx.x;
  if (e >= E) return;
  int p = atomicAdd(&cur[dst[e]], 1);
  srcs[p] = src[e];
  ets[p] = et[e];
  norms[p] = norm[e];
}

// ---------------------------------------------------------------------------
// CSR aggregation: one node per 16 lanes (16 nodes / 256-thread block ->
// 8x node concurrency vs 2/block). Lane owns 8 bases = 128B contiguous of
// h, w (L2) and out. No pointer chase: contiguous sorted edge metadata.
// ---------------------------------------------------------------------------
__global__ __launch_bounds__(256) void edge_agg_csr(
    const int* __restrict__ ns, const int* __restrict__ srcs,
    const int* __restrict__ ets, const float* __restrict__ norms,
    const float* __restrict__ emb, const float* __restrict__ W,
    float* __restrict__ out, int N) {
  const int grp = blockIdx.x * 16 + (threadIdx.x >> 4);
  if (grp >= N) return;
  const int l = threadIdx.x & 15;
  int j = ns[grp];
  const int end = ns[grp + 1];
  if (j == end) return;                 // out already holds GEMM result

  f32x4 a[8] = {};
  for (; j < end; ++j) {
    const int s = srcs[j];
    const int r = ets[j];
    const float nrm = norms[j];
    const f32x4* hp = (const f32x4*)(emb + (size_t)s * H_DIM) + l * 8;
    const f32x4* wp = (const f32x4*)W + ((size_t)r * NUM_BASES + l * 8) * 4;
#pragma unroll
    for (int b = 0; b < 8; ++b) {
      const f32x4 h = hp[b];
      const f32x4 w0 = wp[b * 4 + 0];
      const f32x4 w1 = wp[b * 4 + 1];
      const f32x4 w2 = wp[b * 4 + 2];
      const f32x4 w3 = wp[b * 4 + 3];
      a[b] += (h.x * w0 + h.y * w1 + h.z * w2 + h.w * w3) * nrm;
    }
  }
  f32x4* op = (f32x4*)(out + (size_t)grp * H_DIM) + l * 8;
#pragma unroll
  for (int b = 0; b < 8; ++b) op[b] += a[b];
}

// ---------------------------------------------------------------------------
// Tier-1 fallback kernels (R2-measured path) + tier-2 (R0 path)
// ---------------------------------------------------------------------------
__global__ void init_head(int* head, int N) {
  int i = blockIdx.x * 256 + threadIdx.x;
  if (i < N) head[i] = -1;
}

__global__ void fill_ll(const int* __restrict__ dst, int* head, int* next, int E) {
  int e = blockIdx.x * 256 + threadIdx.x;
  if (e < E) next[e] = atomicExch(&head[dst[e]], e);
}

__device__ __forceinline__ void edge_fma(const float* __restrict__ emb,
                                         const float* __restrict__ W,
                                         int s, int r, int b, float nrm,
                                         float4& a) {
  const float4 h = *(const float4*)(emb + (size_t)s * H_DIM + b * 4);
  const float4* w = (const float4*)(W + ((size_t)r * NUM_BASES + b) * 16);
  const float4 w0 = w[0], w1 = w[1], w2 = w[2], w3 = w[3];
  a.x += nrm * (h.x * w0.x + h.y * w1.x + h.z * w2.x + h.w * w3.x);
  a.y += nrm * (h.x * w0.y + h.y * w1.y + h.z * w2.y + h.w * w3.y);
  a.z += nrm * (h.x * w0.z + h.y * w1.z + h.z * w2.z + h.w * w3.z);
  a.w += nrm * (h.x * w0.w + h.y * w1.w + h.z * w2.w + h.w * w3.w);
}

__global__ __launch_bounds__(256) void edge_agg(
    const int* __restrict__ head, const int* __restrict__ next,
    const int* __restrict__ src, const int* __restrict__ et,
    const float* __restrict__ norm, const float* __restrict__ emb,
    const float* __restrict__ W, float* __restrict__ out, int N) {
  const int node = blockIdx.x * 2 + (threadIdx.x >> 7);
  if (node >= N) return;
  const int b = threadIdx.x & 127;
  int e = head[node];
  if (e < 0) return;
  float4 a = make_float4(0.f, 0.f, 0.f, 0.f);
  while (e >= 0) {
    const int s = src[e];
    const int r = et[e];
    const float nrm = norm[e];
    edge_fma(emb, W, s, r, b, nrm, a);
    e = next[e];
  }
  float4* op = (float4*)(out + (size_t)node * H_DIM + b * 4);
  float4 cur = *op;
  cur.x += a.x; cur.y += a.y; cur.z += a.z; cur.w += a.w;
  *op = cur;
}

__global__ __launch_bounds__(256) void mfma_gemm(
    const float* __restrict__ A, const short* __restrict__ Bt_hi,
    const short* __restrict__ Bt_lo, const float* __restrict__ bias,
    float* __restrict__ C, int M) {
  __shared__ short sAh[8192], sAl[8192], sBh[8192], sBl[8192];
  const int tid = threadIdx.x;
  const int lane = tid & 63;
  const int wave = tid >> 6;
  const int col0 = blockIdx.x * 128;
  const int row0 = blockIdx.y * 128;
  const int wm = (wave >> 1) * 64;
  const int wn = (wave & 1) * 64;
  const int l15 = lane & 15;
  const int l4 = lane >> 4;
  f32x4 acc[4][4] = {};
  for (int k0 = 0; k0 < H_DIM; k0 += 64) {
#pragma unroll
    for (int q = 0; q < 8; ++q) {
      const int f = tid + q * 256;
      const int row = f >> 4;
      const int col = (f & 15) * 4;
      const int si = ((row << 6) + col) ^ ((row & 7) << 3);
      float4 v = make_float4(0.f, 0.f, 0.f, 0.f);
      const int grow = row0 + row;
      if (grow < M) v = *(const float4*)(A + (size_t)grow * H_DIM + k0 + col);
      short h0 = f32_bf16(v.x), h1 = f32_bf16(v.y), h2 = f32_bf16(v.z), h3 = f32_bf16(v.w);
      short e0 = f32_bf16(v.x - bf16_f32(h0)), e1 = f32_bf16(v.y - bf16_f32(h1));
      short e2 = f32_bf16(v.z - bf16_f32(h2)), e3 = f32_bf16(v.w - bf16_f32(h3));
      *(short4*)&sAh[si] = make_short4(h0, h1, h2, h3);
      *(short4*)&sAl[si] = make_short4(e0, e1, e2, e3);
      *(short4*)&sBh[si] = *(const short4*)(Bt_hi + (size_t)(col0 + row) * H_DIM + k0 + col);
      *(short4*)&sBl[si] = *(const short4*)(Bt_lo + (size_t)(col0 + row) * H_DIM + k0 + col);
    }
    __syncthreads();
#pragma unroll
    for (int kk = 0; kk < 2; ++kk) {
      bf16x8 ah[4], al[4], bh[4], bl[4];
      const int cbase = kk * 32 + l4 * 8;
#pragma unroll
      for (int i = 0; i < 4; ++i) {
        const int ra = wm + 16 * i + l15;
        const int sia = ((ra << 6) + cbase) ^ ((ra & 7) << 3);
        ah[i] = *(const bf16x8*)&sAh[sia];
        al[i] = *(const bf16x8*)&sAl[sia];
        const int rb = wn + 16 * i + l15;
        const int sib = ((rb << 6) + cbase) ^ ((rb & 7) << 3);
        bh[i] = *(const bf16x8*)&sBh[sib];
        bl[i] = *(const bf16x8*)&sBl[sib];
      }
#pragma unroll
      for (int i = 0; i < 4; ++i)
#pragma unroll
        for (int jj = 0; jj < 4; ++jj) {
          acc[i][jj] = __builtin_amdgcn_mfma_f32_16x16x32_bf16(ah[i], bh[jj], acc[i][jj], 0, 0, 0);
          acc[i][jj] = __builtin_amdgcn_mfma_f32_16x16x32_bf16(ah[i], bl[jj], acc[i][jj], 0, 0, 0);
          acc[i][jj] = __builtin_amdgcn_mfma_f32_16x16x32_bf16(al[i], bh[jj], acc[i][jj], 0, 0, 0);
        }
    }
    __syncthreads();
  }
  float bv[4];
#pragma unroll
  for (int jj = 0; jj < 4; ++jj) bv[jj] = bias[col0 + wn + 16 * jj + l15];
#pragma unroll
  for (int i = 0; i < 4; ++i) {
#pragma unroll
    for (int r = 0; r < 4; ++r) {
      const int grow = row0 + wm + 16 * i + l4 * 4 + r;
      if (grow < M) {
#pragma unroll
        for (int jj = 0; jj < 4; ++jj)
          C[(size_t)grow * H_DIM + col0 + wn + 16 * jj + l15] = acc[i][jj][r] + bv[jj];
      }
    }
  }
}

__global__ __launch_bounds__(256) void selfloop_gemm(
    const float* __restrict__ A, const float* __restrict__ B,
    const float* __restrict__ bias, float* __restrict__ C, int M) {
  __shared__ float As[32][65];
  __shared__ float Bs[32][64];
  const int tid = threadIdx.x;
  const int row0 = blockIdx.x * 64;
  const int col0 = blockIdx.y * 64;
  const int tx = tid & 15;
  const int ty = tid >> 4;
  float acc[4][4] = {};
  for (int k0 = 0; k0 < H_DIM; k0 += 32) {
#pragma unroll
    for (int q = 0; q < 2; ++q) {
      const int f = tid + q * 256;
      const int kk = (f & 7) * 4;
      const int r = f >> 3;
      const int grow = row0 + r;
      float4 v = make_float4(0.f, 0.f, 0.f, 0.f);
      if (grow < M) v = *(const float4*)(A + (size_t)grow * H_DIM + k0 + kk);
      As[kk + 0][r] = v.x; As[kk + 1][r] = v.y; As[kk + 2][r] = v.z; As[kk + 3][r] = v.w;
    }
#pragma unroll
    for (int q = 0; q < 2; ++q) {
      const int f = tid + q * 256;
      const int nn = (f & 15) * 4;
      const int kk = f >> 4;
      *(float4*)(&Bs[kk][nn]) = *(const float4*)(B + (size_t)(k0 + kk) * H_DIM + col0 + nn);
    }
    __syncthreads();
#pragma unroll
    for (int kk = 0; kk < 32; ++kk) {
      float a[4];
#pragma unroll
      for (int i = 0; i < 4; ++i) a[i] = As[kk][ty * 4 + i];
      const float4 bvv = *(const float4*)(&Bs[kk][tx * 4]);
      const float bb[4] = {bvv.x, bvv.y, bvv.z, bvv.w};
#pragma unroll
      for (int i = 0; i < 4; ++i)
#pragma unroll
        for (int jj = 0; jj < 4; ++jj) acc[i][jj] = fmaf(a[i], bb[jj], acc[i][jj]);
    }
    __syncthreads();
  }
  const float4 bz = *(const float4*)(bias + col0 + tx * 4);
#pragma unroll
  for (int i = 0; i < 4; ++i) {
    const int grow = row0 + ty * 4 + i;
    if (grow < M) {
      float4 o;
      o.x = acc[i][0] + bz.x; o.y = acc[i][1] + bz.y;
      o.z = acc[i][2] + bz.z; o.w = acc[i][3] + bz.w;
      *(float4*)(C + (size_t)grow * H_DIM + col0 + tx * 4) = o;
    }
  }
}

__global__ __launch_bounds__(256) void edge_message(
    const int* __restrict__ src, const int* __restrict__ dst,
    const int* __restrict__ etypes, const float* __restrict__ norm,
    const float* __restrict__ emb, const float* __restrict__ W,
    float* __restrict__ out, int nE) {
  const int b = threadIdx.x & 127;
  const int e = blockIdx.x * 2 + (threadIdx.x >> 7);
  if (e >= nE) return;
  const int s = src[e];
  const int d = dst[e];
  const int r = etypes[e];
  const float nrm = norm[e];
  const float4 h = *(const float4*)(emb + (size_t)s * H_DIM + b * 4);
  const float4* w = (const float4*)(W + ((size_t)r * NUM_BASES + b) * 16);
  const float4 w0 = w[0], w1 = w[1], w2 = w[2], w3 = w[3];
  float* op = out + (size_t)d * H_DIM + b * 4;
  atomicAdd(op + 0, (h.x * w0.x + h.y * w1.x + h.z * w2.x + h.w * w3.x) * nrm);
  atomicAdd(op + 1, (h.x * w0.y + h.y * w1.y + h.z * w2.y + h.w * w3.y) * nrm);
  atomicAdd(op + 2, (h.x * w0.z + h.y * w1.z + h.z * w2.z + h.w * w3.z) * nrm);
  atomicAdd(op + 3, (h.x * w0.w + h.y * w1.w + h.z * w2.w + h.w * w3.w) * nrm);
}

// ---------------------------------------------------------------------------
extern "C" void kernel_launch(void* const* d_in, const int* in_sizes, int n_in,
                              void* d_out, int out_size, void* d_ws, size_t ws_size,
                              hipStream_t stream) {
  const int* src = (const int*)d_in[1];
  const int* dst = (const int*)d_in[2];
  const int* etypes = (const int*)d_in[3];
  const float* norm = (const float*)d_in[4];
  const float* emb = (const float*)d_in[5];
  const float* weight = (const float*)d_in[6];
  const float* loop_weight = (const float*)d_in[7];
  const float* bias = (const float*)d_in[8];
  float* out = (float*)d_out;

  const int nE = in_sizes[1];
  const int M = in_sizes[5] / H_DIM;
  const int Mpad = ((M + 127) / 128) * 128;

  // tier-0 ws layout:
  // deg[M] | node_start[M+1] | cursor[M] | src_s[E] | et_s[E] | norm_s[E]
  // | (align) Ah | Al | Bh | Bl
  const size_t int_bytes = (((size_t)(3 * M + 1 + 3 * nE)) * 4 + 255) & ~(size_t)255;
  const size_t a_bytes = (size_t)Mpad * H_DIM * 2;
  const size_t b_bytes = (size_t)H_DIM * H_DIM * 2;
  const size_t ws_t0 = int_bytes + 2 * a_bytes + 2 * b_bytes;
  const size_t ll_bytes = ((size_t)(M + nE) * 4 + 255) & ~(size_t)255;
  const size_t ws_t1 = ll_bytes + 2 * b_bytes;

  if (ws_size >= ws_t0) {
    int* deg = (int*)d_ws;
    int* nsr = deg + M;              // node_start [M+1]
    int* cur = nsr + (M + 1);
    int* srcs = cur + M;
    int* ets = srcs + nE;
    float* norms = (float*)(ets + nE);
    short* Ah = (short*)((char*)d_ws + int_bytes);
    short* Al = Ah + (size_t)Mpad * H_DIM;
    short* Bh = Al + (size_t)Mpad * H_DIM;
    short* Bl = Bh + (size_t)H_DIM * H_DIM;

    aprep<<<Mpad / 2, 256, 0, stream>>>(emb, Ah, Al, M, Mpad);
    dim3 bg(H_DIM / 32, H_DIM / 32);
    bprep<<<bg, 256, 0, stream>>>(loop_weight, Bh, Bl);

    zero_i32<<<(M + 255) / 256, 256, 0, stream>>>(deg, M);
    count_deg<<<(nE + 255) / 256, 256, 0, stream>>>(dst, deg, nE);
    scan_deg<<<1, 1024, 0, stream>>>(deg, nsr, cur, M);
    scatter_edges<<<(nE + 255) / 256, 256, 0, stream>>>(dst, src, etypes, norm,
                                                        cur, srcs, ets, norms, nE);

    const int nwg = (Mpad / 128) * 4;
    mfma_gemm4<<<nwg, 256, 0, stream>>>(Ah, Al, Bh, Bl, bias, out, M);

    edge_agg_csr<<<(M + 15) / 16, 256, 0, stream>>>(nsr, srcs, ets, norms,
                                                    emb, weight, out, M);
  } else if (ws_size >= ws_t1) {
    int* head = (int*)d_ws;
    int* next = head + M;
    short* Bh = (short*)((char*)d_ws + ll_bytes);
    short* Bl = Bh + (size_t)H_DIM * H_DIM;

    dim3 bg(H_DIM / 32, H_DIM / 32);
    bprep<<<bg, 256, 0, stream>>>(loop_weight, Bh, Bl);
    init_head<<<(M + 255) / 256, 256, 0, stream>>>(head, M);
    fill_ll<<<(nE + 255) / 256, 256, 0, stream>>>(dst, head, next, nE);

    dim3 gg(H_DIM / 128, (Mpad / 128));
    mfma_gemm<<<gg, 256, 0, stream>>>(emb, Bh, Bl, bias, out, M);

    edge_agg<<<(M + 1) / 2, 256, 0, stream>>>(head, next, src, etypes, norm,
                                              emb, weight, out, M);
  } else {
    dim3 ggrid((M + 63) / 64, H_DIM / 64);
    selfloop_gemm<<<ggrid, 256, 0, stream>>>(emb, loop_weight, bias, out, M);
    edge_message<<<(nE + 1) / 2, 256, 0, stream>>>(src, dst, etypes, norm, emb,
                                                   weight, out, nE);
  }
}